// Round 7
// baseline (100.015 us; speedup 1.0000x reference)
//
#include <hip/hip_runtime.h>

// out[b,e,j] = bias[j] + sum_k weight[k,j] * y[b, e+k-7, j]
// y[b,e',j]  = sum_{i<=j} x[b,e',i] * dv^(j-i)   (decayed prefix scan over features)
// dv = clip(decay_value[1], 0.9, 1.0); y rows with e' < 0 are zero.
//
// R7: R4's fused structure + async direct-to-LDS staging. R1-R6 all plateaued
// at kernel ~30 us regardless of structure: per-row VGPR loads gave tiny
// memory-level parallelism (need ~9.2 KB/CU in flight for 6.3 TB/s at ~900 cyc
// latency). Phase 0 now issues ~20 global_load_lds (width=16) per wave
// back-to-back -- ~80 KB in flight per block, no VGPR cost. Scan reads x from
// LDS (12 cyc) and rewrites y in place; conv unchanged.

#define B_    8
#define E_    2048
#define DIM_  512
#define K_    8
#define TILE_E 32
#define NROWS  (TILE_E + K_ - 1)   // 39 rows * 2 KB = 79872 B LDS; 2 blocks/CU

__device__ __forceinline__ void load_lds16(const float* g, float* l) {
    // lane i's 16 B land at lds_base + 16*i (wave-uniform base, m104/m108 rule)
    __builtin_amdgcn_global_load_lds(
        (const __attribute__((address_space(1))) void*)g,
        (__attribute__((address_space(3))) void*)l, 16, 0, 0);
}

__global__ __launch_bounds__(256) void krl_fused(
    const float* __restrict__ x,
    const float* __restrict__ weight,
    const float* __restrict__ bias,
    const float* __restrict__ decay,
    float* __restrict__ out)
{
    __shared__ float yls[NROWS][DIM_];   // unpadded: DMA lane order == row order

    const int tile = blockIdx.x;
    const int b    = blockIdx.y;
    const int e0   = tile * TILE_E;      // E_ % TILE_E == 0

    const int t    = threadIdx.x;
    const int lane = t & 63;
    const int wave = t >> 6;

    // ---- Phase 0: async-stage all 39 x-rows into LDS, max MLP ----
    // Each row = 2 KB = 2 DMA insts (64 lanes x 16 B). ~10 rows per wave,
    // all issued with no intervening waits.
    for (int r = wave; r < NROWS; r += 4) {
        const int eg = e0 - (K_ - 1) + r;        // wave-uniform condition
        if (eg >= 0) {
            const float* xrow = x + ((size_t)b * E_ + eg) * DIM_ + lane * 4;
            load_lds16(xrow,       &yls[r][0]);
            load_lds16(xrow + 256, &yls[r][256]);
        } else {                                 // zero pad rows (tile 0 only)
            const float4 z = make_float4(0.f, 0.f, 0.f, 0.f);
            *(float4*)(&yls[r][lane * 8])     = z;
            *(float4*)(&yls[r][lane * 8 + 4]) = z;
        }
    }

    float dv = decay[1];
    dv = fminf(fmaxf(dv, 0.9f), 1.0f);
    const float dv2 = dv * dv;
    const float dv4 = dv2 * dv2;
    const float dv8 = dv4 * dv4;

    __syncthreads();   // drains vmcnt(0): staged rows visible block-wide

    // ---- Phase 1: in-place decayed prefix scan of each row (LDS -> LDS) ----
    for (int r = wave; r < NROWS; r += 4) {
        const float4 a0 = *(const float4*)(&yls[r][lane * 8]);
        const float4 a1 = *(const float4*)(&yls[r][lane * 8 + 4]);
        const float xv[8] = {a0.x, a0.y, a0.z, a0.w, a1.x, a1.y, a1.z, a1.w};

        float tl[8];
        tl[0] = xv[0];
        #pragma unroll
        for (int m = 1; m < 8; ++m) tl[m] = fmaf(dv, tl[m - 1], xv[m]);

        // cross-lane: Y_l = T_l + dv^8 * Y_{l-1} (Kogge-Stone over 64 lanes)
        float v  = tl[7];
        float ap = dv8;
        #pragma unroll
        for (int off = 1; off < 64; off <<= 1) {
            float up = __shfl_up(v, off, 64);
            if (lane >= off) v = fmaf(ap, up, v);
            ap *= ap;
        }
        float carry = __shfl_up(v, 1, 64);       // y[8*lane - 1]
        if (lane == 0) carry = 0.f;
        float dp = dv;
        #pragma unroll
        for (int m = 0; m < 8; ++m) { tl[m] = fmaf(dp, carry, tl[m]); dp *= dv; }

        *(float4*)(&yls[r][lane * 8])     = make_float4(tl[0], tl[1], tl[2], tl[3]);
        *(float4*)(&yls[r][lane * 8 + 4]) = make_float4(tl[4], tl[5], tl[6], tl[7]);
    }

    // Phase-2 operands: issue before the barrier so latency hides under it.
    const int jf = (t & 127) * 4;
    float4 w[K_];
    #pragma unroll
    for (int k = 0; k < K_; ++k) w[k] = *(const float4*)(weight + k * DIM_ + jf);
    const float4 bi = *(const float4*)(bias + jf);

    __syncthreads();

    // ---- Phase 2: depthwise causal conv (K=8) along E, per feature chunk ----
    const int g = t >> 7;
    for (int te = g; te < TILE_E; te += 2) {
        float4 acc = bi;
        #pragma unroll
        for (int k = 0; k < K_; ++k) {
            const float4 yv = *(const float4*)(&yls[te + k][jf]);
            acc.x = fmaf(w[k].x, yv.x, acc.x);
            acc.y = fmaf(w[k].y, yv.y, acc.y);
            acc.z = fmaf(w[k].z, yv.z, acc.z);
            acc.w = fmaf(w[k].w, yv.w, acc.w);
        }
        *(float4*)(out + ((size_t)b * E_ + e0 + te) * DIM_ + jf) = acc;
    }
}

extern "C" void kernel_launch(void* const* d_in, const int* in_sizes, int n_in,
                              void* d_out, int out_size, void* d_ws, size_t ws_size,
                              hipStream_t stream) {
    const float* x      = (const float*)d_in[0];
    const float* weight = (const float*)d_in[1];
    const float* bias   = (const float*)d_in[2];
    const float* decay  = (const float*)d_in[3];
    float* out = (float*)d_out;

    dim3 grid(E_ / TILE_E, B_);   // 64 x 8 = 512 blocks == 2 blocks/CU exactly
    dim3 block(256);
    krl_fused<<<grid, block, 0, stream>>>(x, weight, bias, decay, out);
}

// Round 8
// 99.911 us; speedup vs baseline: 1.0010x; 1.0010x over previous
//
#include <hip/hip_runtime.h>

// out[b,e,j] = bias[j] + sum_k weight[k,j] * y[b, e+k-7, j]
// y[b,e',j]  = sum_{i<=j} x[b,e',i] * dv^(j-i)   (decayed prefix scan over features)
// dv = clip(decay_value[1], 0.9, 1.0); y rows with e' < 0 are zero.
//
// R8: R5's barrier-free register-window (best so far, 91.8) with the per-row
// serial chains removed: decay powers dvp[]/aps[] precomputed (fixup = 8
// independent FMAs), explicit 2-deep load pipeline (row r+1 loads issue ahead
// of row r's scan chain), fully straight-line body (padded rows scan zeros),
// and nontemporal output stores (write-once; keep L2/L3 for the halo x reuse).

#define B_    8
#define E_    2048
#define DIM_  512
#define K_    8
#define SE_   8                     // output rows per wave
#define NR_   (SE_ + K_ - 1)        // 15 scan rows per wave

typedef float vf4 __attribute__((ext_vector_type(4)));

__global__ __launch_bounds__(256) void krl_win(
    const float* __restrict__ x,
    const float* __restrict__ weight,
    const float* __restrict__ bias,
    const float* __restrict__ decay,
    float* __restrict__ out)
{
    const int t    = threadIdx.x;
    const int lane = t & 63;
    const int wave = t >> 6;
    const int wid  = blockIdx.x * 4 + wave;      // [0, 2048)
    const int b    = wid >> 8;                   // 256 strips per b
    const int e0   = (wid & 255) << 3;

    float dv = decay[1];
    dv = fminf(fmaxf(dv, 0.9f), 1.0f);

    // dvp[m] = dv^(m+1) (carry fixup); aps[s] = dv^(8<<s) (Kogge-Stone hops)
    float dvp[8];
    dvp[0] = dv;
    #pragma unroll
    for (int m = 1; m < 8; ++m) dvp[m] = dvp[m - 1] * dv;
    float aps[6];
    aps[0] = dvp[7];
    #pragma unroll
    for (int s = 1; s < 6; ++s) aps[s] = aps[s - 1] * aps[s - 1];

    const int jf = lane * 8;                     // 8 contiguous features per lane

    // loop-invariant weights + bias in registers
    float wv[K_][8];
    #pragma unroll
    for (int k = 0; k < K_; ++k) {
        const float4 p0 = *(const float4*)(weight + k * DIM_ + jf);
        const float4 p1 = *(const float4*)(weight + k * DIM_ + jf + 4);
        wv[k][0] = p0.x; wv[k][1] = p0.y; wv[k][2] = p0.z; wv[k][3] = p0.w;
        wv[k][4] = p1.x; wv[k][5] = p1.y; wv[k][6] = p1.z; wv[k][7] = p1.w;
    }
    const float4 bi0 = *(const float4*)(bias + jf);
    const float4 bi1 = *(const float4*)(bias + jf + 4);

    float a[SE_][8];
    #pragma unroll
    for (int m = 0; m < SE_; ++m)
        #pragma unroll
        for (int j = 0; j < 8; ++j) a[m][j] = 0.f;

    const float* xb = x + (size_t)b * E_ * DIM_ + jf;
    float*       ob = out + ((size_t)b * E_ + e0) * DIM_ + jf;

    // ---- 2-deep pipelined row loop: load r+1, then scan/fold r ----
    float4 c0, c1, n0, n1;
    {
        const int eg  = e0 - (K_ - 1);
        const int egc = eg < 0 ? 0 : eg;
        const float4* xp = (const float4*)(xb + (size_t)egc * DIM_);
        c0 = xp[0]; c1 = xp[1];
        if (eg < 0) { c0 = make_float4(0.f, 0.f, 0.f, 0.f); c1 = c0; }
    }

    #pragma unroll
    for (int r = 0; r < NR_; ++r) {
        if (r + 1 < NR_) {
            const int eg  = e0 - (K_ - 1) + r + 1;
            const int egc = eg < 0 ? 0 : eg;
            const float4* xp = (const float4*)(xb + (size_t)egc * DIM_);
            n0 = xp[0]; n1 = xp[1];
            if (eg < 0) { n0 = make_float4(0.f, 0.f, 0.f, 0.f); n1 = n0; }
        }

        const float xv[8] = {c0.x, c0.y, c0.z, c0.w, c1.x, c1.y, c1.z, c1.w};

        // lane-local decayed scan (padded rows scan zeros -> y stays zero)
        float tl[8];
        tl[0] = xv[0];
        #pragma unroll
        for (int m = 1; m < 8; ++m) tl[m] = fmaf(dv, tl[m - 1], xv[m]);

        // cross-lane: Y_l = T_l + dv^8 * Y_{l-1} (Kogge-Stone, hop consts in regs)
        float v = tl[7];
        #pragma unroll
        for (int s = 0; s < 6; ++s) {
            const int off = 1 << s;
            float up = __shfl_up(v, off, 64);
            if (lane >= off) v = fmaf(aps[s], up, v);
        }
        float carry = __shfl_up(v, 1, 64);       // y[jf - 1]
        if (lane == 0) carry = 0.f;
        #pragma unroll
        for (int m = 0; m < 8; ++m) tl[m] = fmaf(dvp[m], carry, tl[m]);

        // fold y-row r into pending accumulators: output e0+m takes tap r-m
        #pragma unroll
        for (int m = 0; m < SE_; ++m) {
            if (m <= r && r - m <= K_ - 1) {     // static after unroll
                const int k = r - m;
                #pragma unroll
                for (int j = 0; j < 8; ++j)
                    a[m][j] = fmaf(wv[k][j], tl[j], a[m][j]);
            }
        }

        // output row e0 + (r-7) completes after its last tap (scan row r)
        if (r >= K_ - 1) {
            const int m = r - (K_ - 1);
            vf4 o0 = {a[m][0] + bi0.x, a[m][1] + bi0.y,
                      a[m][2] + bi0.z, a[m][3] + bi0.w};
            vf4 o1 = {a[m][4] + bi1.x, a[m][5] + bi1.y,
                      a[m][6] + bi1.z, a[m][7] + bi1.w};
            __builtin_nontemporal_store(o0, (vf4*)(ob + (size_t)m * DIM_));
            __builtin_nontemporal_store(o1, (vf4*)(ob + (size_t)m * DIM_ + 4));
        }

        c0 = n0; c1 = n1;
    }
}

extern "C" void kernel_launch(void* const* d_in, const int* in_sizes, int n_in,
                              void* d_out, int out_size, void* d_ws, size_t ws_size,
                              hipStream_t stream) {
    const float* x      = (const float*)d_in[0];
    const float* weight = (const float*)d_in[1];
    const float* bias   = (const float*)d_in[2];
    const float* decay  = (const float*)d_in[3];
    float* out = (float*)d_out;

    // 2048 waves = 512 blocks x 4 waves; no LDS; all resident in one round.
    krl_win<<<dim3((B_ * (E_ / SE_)) / 4), dim3(256), 0, stream>>>(
        x, weight, bias, decay, out);
}

// Round 9
// 91.083 us; speedup vs baseline: 1.0981x; 1.0969x over previous
//
#include <hip/hip_runtime.h>

// out[b,e,j] = bias[j] + sum_k weight[k,j] * y[b, e+k-7, j]
// y[b,e',j]  = sum_{i<=j} x[b,e',i] * dv^(j-i)   (decayed prefix scan over features)
// dv = clip(decay_value[1], 0.9, 1.0); y rows with e' < 0 are zero.
//
// R9: transposed two-level scan. All prior rounds (R1-R8) shared a 64-lane
// Kogge-Stone per row: 7 dependent ds_bpermute hops x 15-39 rows per wave --
// the one structural constant of the ~32 us plateau. Now each lane owns a
// 128-feature SEGMENT (lane = row + 16*seg): lane-local Horner for segment
// ends, one 2-hop shuffle combine per row, lane-local carry pass. Cross-lane
// ops: 3 per row instead of 7 per 8 features. Chained FMAs restructured via
// d1..d4 powers: 1 chain-FMA per 4 elements. Conv uses a rolling register
// window (each y row read once from LDS). Padded LDS stride 516 floats:
// staging/conv conflict-free, scan reads ~2-way (free, m136).

#define B_     8
#define E_     2048
#define DIM_   512
#define K_     8
#define TILE_E 32
#define NROWS  (TILE_E + K_ - 1)     // 39
#define LSTR   516                   // floats; 2064 B row stride (16B aligned)
#define NF4    (NROWS * (DIM_ / 4))  // 4992 float4 staging chunks

__global__ __launch_bounds__(256) void krl_t(
    const float* __restrict__ x,
    const float* __restrict__ weight,
    const float* __restrict__ bias,
    const float* __restrict__ decay,
    float* __restrict__ out)
{
    __shared__ float yls[NROWS * LSTR];   // 80,496 B -> 2 blocks/CU

    const int t  = threadIdx.x;
    const int b  = blockIdx.y;
    const int e0 = blockIdx.x * TILE_E;   // E_ % TILE_E == 0

    // ---- Phase 0: stage 39 x-rows into padded LDS, coalesced float4 ----
    const int ebase = e0 - (K_ - 1);
    for (int i = t; i < NF4; i += 256) {
        const int r  = i >> 7;            // row 0..38
        const int f4 = i & 127;
        const int eg = ebase + r;
        float4 v = make_float4(0.f, 0.f, 0.f, 0.f);
        if (eg >= 0)
            v = *(const float4*)(x + ((size_t)b * E_ + eg) * DIM_ + f4 * 4);
        *(float4*)(&yls[r * LSTR + f4 * 4]) = v;
    }

    float dv = decay[1];
    dv = fminf(fmaxf(dv, 0.9f), 1.0f);
    const float d1 = dv, d2 = dv * dv, d3 = d2 * dv, d4 = d2 * d2;
    float d128 = d4;                      // dv^4 -> square 5x = dv^128
    d128 *= d128; d128 *= d128; d128 *= d128; d128 *= d128; d128 *= d128;
    const float d256 = d128 * d128;

    __syncthreads();

    // ---- Phase 1: transposed two-level decayed scan (in-place in LDS) ----
    const int lane = t & 63, wave = t >> 6;
    const int r16 = lane & 15, seg = lane >> 4;
    const int row = wave * 16 + r16;      // waves 0,1 full; wave 2: 7 rows; wave 3 idle
    if (row < NROWS) {
        float* sp = &yls[row * LSTR + seg * 128];

        // pass 1: segment-end Horner  E = sum_m x[m] * dv^(127-m)
        float E = 0.f;
        #pragma unroll 8
        for (int q = 0; q < 32; ++q) {
            const float4 v = *(const float4*)(sp + 4 * q);
            const float p = fmaf(d3, v.x, fmaf(d2, v.y, fmaf(d1, v.z, v.w)));
            E = fmaf(d4, E, p);           // 1 chained FMA per 4 elements
        }

        // level 2: carry across the row's 4 segments (2 shuffle hops)
        float S = E;
        float u1 = __shfl_up(S, 16, 64); if (seg >= 1) S = fmaf(d128, u1, S);
        float u2 = __shfl_up(S, 32, 64); if (seg >= 2) S = fmaf(d256, u2, S);
        float C = __shfl_up(S, 16, 64);  if (seg == 0) C = 0.f;   // S_{s-1}

        // pass 2: carry-propagating scan, 1 chained FMA per 4 elements
        float prev = C;
        #pragma unroll 8
        for (int q = 0; q < 32; ++q) {
            const float4 v = *(const float4*)(sp + 4 * q);
            const float p01   = fmaf(d1, v.x, v.y);
            const float p012  = fmaf(d1, p01, v.z);
            const float p0123 = fmaf(d1, p012, v.w);
            float4 yv;
            yv.x = fmaf(d1, prev, v.x);
            yv.y = fmaf(d2, prev, p01);
            yv.z = fmaf(d3, prev, p012);
            yv.w = fmaf(d4, prev, p0123);
            prev = yv.w;
            *(float4*)(sp + 4 * q) = yv;
        }
    }

    // Phase-2 operands issued before the barrier (latency hides under it).
    const int j  = t & 127, h = t >> 7;
    const int jf = j * 4;
    float4 w[K_];
    #pragma unroll
    for (int k = 0; k < K_; ++k) w[k] = *(const float4*)(weight + k * DIM_ + jf);
    const float4 bi = *(const float4*)(bias + jf);

    __syncthreads();

    // ---- Phase 2: rolling-window conv; each y row read ONCE from LDS ----
    const int te0 = h * 16;               // h=0: outputs 0..15, h=1: 16..31
    float4 win[K_];
    #pragma unroll
    for (int k = 0; k < 7; ++k)
        win[k] = *(const float4*)(&yls[(te0 + k) * LSTR + jf]);

    #pragma unroll
    for (int i = 0; i < 16; ++i) {
        const int te = te0 + i;
        win[7] = *(const float4*)(&yls[(te + 7) * LSTR + jf]);
        float4 acc = bi;
        #pragma unroll
        for (int k = 0; k < K_; ++k) {
            acc.x = fmaf(w[k].x, win[k].x, acc.x);
            acc.y = fmaf(w[k].y, win[k].y, acc.y);
            acc.z = fmaf(w[k].z, win[k].z, acc.z);
            acc.w = fmaf(w[k].w, win[k].w, acc.w);
        }
        *(float4*)(out + ((size_t)b * E_ + e0 + te) * DIM_ + jf) = acc;
        #pragma unroll
        for (int k = 0; k < 7; ++k) win[k] = win[k + 1];   // renamed, free
    }
}

extern "C" void kernel_launch(void* const* d_in, const int* in_sizes, int n_in,
                              void* d_out, int out_size, void* d_ws, size_t ws_size,
                              hipStream_t stream) {
    const float* x      = (const float*)d_in[0];
    const float* weight = (const float*)d_in[1];
    const float* bias   = (const float*)d_in[2];
    const float* decay  = (const float*)d_in[3];
    float* out = (float*)d_out;

    dim3 grid(E_ / TILE_E, B_);   // 64 x 8 = 512 blocks = 2 blocks/CU exactly
    dim3 block(256);
    krl_t<<<grid, block, 0, stream>>>(x, weight, bias, decay, out);
}